// Round 1
// baseline (524.826 us; speedup 1.0000x reference)
//
#include <hip/hip_runtime.h>

namespace {
constexpr int NP      = 64;      // pulses
constexpr int BATCH_N = 16384;   // batch
constexpr int NS      = 21;      // EPG states
constexpr int CHAN    = BATCH_N * NS;        // 344064 elems per channel plane
constexpr long long STEP = 5LL * CHAN;       // per-pulse output stride (elems)
}

// One lane per (batch, state). 3 batch elems per wave: lanes [0,21) -> b+0,
// [21,42) -> b+1, [42,63) -> b+2, lane 63 idle. Gradient shift = shfl by 1;
// the s==0 / s==20 zeroing masks exactly kill the cross-batch shuffle leak.
__global__ __launch_bounds__(256) void epg_kernel(
    const float* __restrict__ flip, const float* __restrict__ ph,
    const float* __restrict__ T1,   const float* __restrict__ T2,
    const float* __restrict__ B0,   const float* __restrict__ B1,
    const int*   __restrict__ TRp,  float* __restrict__ out)
{
  const int lane = threadIdx.x & 63;
  const int wv   = threadIdx.x >> 6;
  const int sub  = lane / 21;            // 0..2 real, 3 = idle lane 63
  const int s    = lane - sub * 21;      // state index 0..20
  const int bg   = (blockIdx.x * 4 + wv) * 3 + sub;
  const bool active = (sub < 3) && (bg < BATCH_N);
  const int  bs  = active ? bg : 0;      // safe load index

  const float TR = (float)TRp[0];
  const float E1 = __expf(-TR / T1[bs]);
  const float E2 = __expf(-TR / T2[bs]);
  const float b1 = B1[bs];
  const float rec = (s == 0) ? (1.0f - E1) : 0.0f;   // Z recovery, k==0 only
  const float phi = 6.283185307179586f * 0.001f * TR * B0[bs];
  float bi, br; __sincosf(phi, &bi, &br);            // eb0p = br + i*bi

  float fpr = 0.f, fpi = 0.f, fmr = 0.f, fmi = 0.f;
  float z = (s == 0) ? 1.0f : 0.0f;

  float* op = out + (long long)bs * NS + s;

  for (int p = 0; p < NP; ++p) {
    const float a = flip[p];     // uniform (scalar) loads
    const float b = ph[p];
    float sa, ca; __sincosf(0.5f * a * b1, &sa, &ca);
    float ei, er; __sincosf(b, &ei, &er);            // eib = er + i*ei
    const float w2r = er * er - ei * ei;             // eib^2
    const float w2i = 2.0f * er * ei;
    const float c2 = ca * ca, s2 = sa * sa, cs = ca * sa;

    // relaxation
    fpr *= E2; fpi *= E2; fmr *= E2; fmi *= E2;
    z = E1 * z + rec;

    // B0 precession: Fp *= eb0p, Fm *= conj(eb0p)
    {
      float t = fpr * br - fpi * bi;
      fpi = fpr * bi + fpi * br; fpr = t;
      float u = fmr * br + fmi * bi;
      fmi = fmi * br - fmr * bi; fmr = u;
    }

    // RF rotation
    const float zcs = cs * z;
    const float fpnr =  c2 * fpr + s2 * (fmr * w2r + fmi * w2i) - zcs * ei;
    const float fpni =  c2 * fpi + s2 * (fmr * w2i - fmi * w2r) + zcs * er;
    const float fmnr =  c2 * fmr + s2 * (fpr * w2r - fpi * w2i) - zcs * ei;
    const float fmni =  c2 * fmi - s2 * (fpr * w2i + fpi * w2r) - zcs * er;
    const float zn   =  cs * ((fpi - fmi) * er - (fpr + fmr) * ei)
                        + (c2 - s2) * z;

    // gradient shift: Fp up one state, Fm down one state
    const float ufpr = __shfl_up(fpnr, 1);
    const float ufpi = __shfl_up(fpni, 1);
    const float dfmr = __shfl_down(fmnr, 1);
    const float dfmi = __shfl_down(fmni, 1);
    fpr = (s == 0)  ? 0.f : ufpr;
    fpi = (s == 0)  ? 0.f : ufpi;
    fmr = (s == 20) ? 0.f : dfmr;
    fmi = (s == 20) ? 0.f : dfmi;
    z = zn;

    if (active) {
      op[0]        = fpr;   // Fp_s.real
      op[CHAN]     = fpi;   // Fp_s.imag
      op[2 * CHAN] = fmr;   // Fm_s.real
      op[3 * CHAN] = fmi;   // Fm_s.imag
      op[4 * CHAN] = zn;    // Z_n
    }
    op += STEP;
  }
}

extern "C" void kernel_launch(void* const* d_in, const int* in_sizes, int n_in,
                              void* d_out, int out_size, void* d_ws, size_t ws_size,
                              hipStream_t stream) {
  const float* flip = (const float*)d_in[0];
  const float* ph   = (const float*)d_in[1];
  const float* T1   = (const float*)d_in[2];
  const float* T2   = (const float*)d_in[3];
  const float* B0   = (const float*)d_in[4];
  const float* B1   = (const float*)d_in[5];
  const int*   TR   = (const int*)d_in[6];
  // d_in[7] = TE, unused by the reference output
  float* out = (float*)d_out;

  const int blocks = (BATCH_N + 11) / 12;   // 12 batch elems per 256-thr block
  epg_kernel<<<blocks, 256, 0, stream>>>(flip, ph, T1, T2, B0, B1, TR, out);
}

// Round 2
// 518.872 us; speedup vs baseline: 1.0115x; 1.0115x over previous
//
#include <hip/hip_runtime.h>

namespace {
constexpr int NP      = 64;       // pulses
constexpr int BATCH_N = 16384;    // batch
constexpr int NS      = 21;       // EPG states
constexpr int BPB     = 12;       // batch elems per 256-thread block
constexpr int CHAN    = BATCH_N * NS;                 // 344064 floats/plane
constexpr unsigned CHANB = (unsigned)CHAN * 4u;       // 1376256 B
constexpr unsigned STEPB = 5u * CHANB;                // 6881280 B per pulse
constexpr int LDSF    = BPB * NS * 5;                 // 1260 floats / buffer
constexpr int NSLOT   = (LDSF + 3) / 4;               // 315 float4 per flush
}

// Compute: one lane per (batch, state); 3 batch elems per wave (3*21=63 lanes,
// lane 63 idle). Gradient shift = shfl by 1; s==0 / s==20 zero-masks absorb
// the cross-batch shuffle leak. Output: staged per-pulse in LDS, flushed as
// 16B-aligned float4 stores (full 64B lines, no partial-line RMW on the
// 0xAA-poisoned output buffer).
__global__ __launch_bounds__(256) void epg_kernel(
    const float* __restrict__ flip, const float* __restrict__ ph,
    const float* __restrict__ T1,   const float* __restrict__ T2,
    const float* __restrict__ B0,   const float* __restrict__ B1,
    const int*   __restrict__ TRp,  float* __restrict__ out)
{
  __shared__ __align__(16) float lds[2][LDSF];   // 10080 B

  const int tid  = threadIdx.x;
  const int lane = tid & 63;
  const int wv   = tid >> 6;
  const int sub  = lane / 21;            // 0..2 real, 3 = idle lane 63
  const int s    = lane - sub * 21;      // state index 0..20
  const int bg   = blockIdx.x * BPB + wv * 3 + sub;
  const bool active = (sub < 3) && (bg < BATCH_N);
  const int  bs  = active ? bg : 0;      // safe load index
  const int  inner = wv * 63 + lane;     // == (wv*3+sub)*21 + s for active

  // ---- flush-slot precompute (fixed per thread) ----
  const int rem = min(BPB, BATCH_N - blockIdx.x * BPB);  // batch in this block
  const unsigned base0 = (unsigned)blockIdx.x * (BPB * NS * 4u); // 1008*blk B
  int      loff[2]; unsigned goff[2]; bool fdo[2];
  #pragma unroll
  for (int k = 0; k < 2; ++k) {
    const int i = tid + k * 256;
    const int c = i / 63;                // channel 0..4
    const int j = i - c * 63;            // float4 index within plane region
    fdo[k]  = (i < NSLOT) && (4 * j < rem * NS);
    loff[k] = c * (BPB * NS) + 4 * j;    // float index into lds buffer
    goff[k] = base0 + (unsigned)c * CHANB + (unsigned)j * 16u;
  }

  // ---- per-lane physics setup ----
  const float TR = (float)TRp[0];
  const float E1 = __expf(-TR / T1[bs]);
  const float E2 = __expf(-TR / T2[bs]);
  const float b1 = B1[bs];
  const float rec = (s == 0) ? (1.0f - E1) : 0.0f;   // Z recovery, k==0 only
  const float phi = 6.283185307179586f * 0.001f * TR * B0[bs];
  float bi, br; __sincosf(phi, &bi, &br);            // eb0p = br + i*bi

  float fpr = 0.f, fpi = 0.f, fmr = 0.f, fmi = 0.f;
  float z = (s == 0) ? 1.0f : 0.0f;

  char* const outb = (char*)out;
  unsigned pbase = 0;
  int buf = 0;

  for (int p = 0; p < NP; ++p) {
    const float a = flip[p];     // uniform (scalar) loads
    const float b = ph[p];
    float sa, ca; __sincosf(0.5f * a * b1, &sa, &ca);
    float ei, er; __sincosf(b, &ei, &er);            // eib = er + i*ei
    const float w2r = er * er - ei * ei;             // eib^2
    const float w2i = 2.0f * er * ei;
    const float c2 = ca * ca, s2 = sa * sa, cs = ca * sa;

    // relaxation
    fpr *= E2; fpi *= E2; fmr *= E2; fmi *= E2;
    z = E1 * z + rec;

    // B0 precession: Fp *= eb0p, Fm *= conj(eb0p)
    {
      float t = fpr * br - fpi * bi;
      fpi = fpr * bi + fpi * br; fpr = t;
      float u = fmr * br + fmi * bi;
      fmi = fmi * br - fmr * bi; fmr = u;
    }

    // RF rotation
    const float zcs = cs * z;
    const float fpnr =  c2 * fpr + s2 * (fmr * w2r + fmi * w2i) - zcs * ei;
    const float fpni =  c2 * fpi + s2 * (fmr * w2i - fmi * w2r) + zcs * er;
    const float fmnr =  c2 * fmr + s2 * (fpr * w2r - fpi * w2i) - zcs * ei;
    const float fmni =  c2 * fmi - s2 * (fpr * w2i + fpi * w2r) - zcs * er;
    const float zn   =  cs * ((fpi - fmi) * er - (fpr + fmr) * ei)
                        + (c2 - s2) * z;

    // gradient shift: Fp up one state, Fm down one state
    const float ufpr = __shfl_up(fpnr, 1);
    const float ufpi = __shfl_up(fpni, 1);
    const float dfmr = __shfl_down(fmnr, 1);
    const float dfmi = __shfl_down(fmni, 1);
    fpr = (s == 0)  ? 0.f : ufpr;
    fpi = (s == 0)  ? 0.f : ufpi;
    fmr = (s == 20) ? 0.f : dfmr;
    fmi = (s == 20) ? 0.f : dfmi;
    z = zn;

    // stage this pulse's output in LDS: layout [c][b][s]
    if (active) {
      float* lb = lds[buf];
      lb[inner]                = fpr;   // Fp_s.real
      lb[BPB * NS + inner]     = fpi;   // Fp_s.imag
      lb[2 * BPB * NS + inner] = fmr;   // Fm_s.real
      lb[3 * BPB * NS + inner] = fmi;   // Fm_s.imag
      lb[4 * BPB * NS + inner] = zn;    // Z_n
    }
    __syncthreads();

    // flush: 16B-aligned float4 stores covering this block's region exactly
    {
      const float* lb = lds[buf];
      #pragma unroll
      for (int k = 0; k < 2; ++k) {
        if (fdo[k]) {
          const float4 v = *(const float4*)&lb[loff[k]];
          *(float4*)(outb + pbase + goff[k]) = v;
        }
      }
    }
    buf ^= 1;
    pbase += STEPB;
  }
}

extern "C" void kernel_launch(void* const* d_in, const int* in_sizes, int n_in,
                              void* d_out, int out_size, void* d_ws, size_t ws_size,
                              hipStream_t stream) {
  const float* flip = (const float*)d_in[0];
  const float* ph   = (const float*)d_in[1];
  const float* T1   = (const float*)d_in[2];
  const float* T2   = (const float*)d_in[3];
  const float* B0   = (const float*)d_in[4];
  const float* B1   = (const float*)d_in[5];
  const int*   TR   = (const int*)d_in[6];
  // d_in[7] = TE, unused by the reference output
  float* out = (float*)d_out;

  const int blocks = (BATCH_N + BPB - 1) / BPB;   // 1366
  epg_kernel<<<blocks, 256, 0, stream>>>(flip, ph, T1, T2, B0, B1, TR, out);
}